// Round 1
// baseline (208.010 us; speedup 1.0000x reference)
//
#include <hip/hip_runtime.h>
#include <hip/hip_bf16.h>

#define B_DIM 4
#define C_DIM 256
#define N_DIM 4096

// ---------------------------------------------------------------------------
// K1: fused channel-mix GEMM.  k[b,r,n] = scale * sum_c Wk[r,c]*X[b,c,n]
//                              v[b,o,n] =         sum_c Wv[o,c]*X[b,c,n]
// 64x64 output tile per block, K-chunks of 32, 4x4 register tile per thread
// for BOTH k and v (X tile in LDS amortized across the two GEMMs).
// ---------------------------------------------------------------------------
__global__ __launch_bounds__(256) void gemm_kv(
    const float* __restrict__ X,
    const float* __restrict__ Wk,
    const float* __restrict__ Wv,
    float* __restrict__ Kout,
    float* __restrict__ Vout)
{
    __shared__ float sWk[32][65];   // [c][r], +1 pad breaks store conflicts
    __shared__ float sWv[32][65];
    __shared__ float sX[32][64];    // [c][n]

    const int b   = blockIdx.z;
    const int r0  = blockIdx.y * 64;
    const int n0  = blockIdx.x * 64;
    const int tid = threadIdx.x;
    const int tx  = tid & 15;       // n-group
    const int ty  = tid >> 4;       // r-group

    const float* Xb = X + (size_t)b * C_DIM * N_DIM;

    float ak[4][4] = {{0.f}};
    float av[4][4] = {{0.f}};

    for (int c0 = 0; c0 < C_DIM; c0 += 32) {
        // stage W tiles transposed: coalesced over c in global, [c][r] in LDS
        {
            int cl = tid & 31;
            int rl = tid >> 5;
            #pragma unroll
            for (int i = 0; i < 8; ++i) {
                int r = rl + i * 8;
                sWk[cl][r] = Wk[(r0 + r) * C_DIM + c0 + cl];
                sWv[cl][r] = Wv[(r0 + r) * C_DIM + c0 + cl];
            }
        }
        // stage X tile: rows contiguous in n -> coalesced
        {
            int nl  = tid & 63;
            int cl0 = tid >> 6;
            #pragma unroll
            for (int i = 0; i < 8; ++i) {
                int c = cl0 + i * 4;
                sX[c][nl] = Xb[(size_t)(c0 + c) * N_DIM + n0 + nl];
            }
        }
        __syncthreads();

        for (int cc = 0; cc < 32; ++cc) {
            float xf[4], kf[4], vf[4];
            #pragma unroll
            for (int j = 0; j < 4; ++j) xf[j] = sX[cc][tx * 4 + j];
            #pragma unroll
            for (int i = 0; i < 4; ++i) {
                kf[i] = sWk[cc][ty * 4 + i];
                vf[i] = sWv[cc][ty * 4 + i];
            }
            #pragma unroll
            for (int i = 0; i < 4; ++i)
                #pragma unroll
                for (int j = 0; j < 4; ++j) {
                    ak[i][j] = fmaf(kf[i], xf[j], ak[i][j]);
                    av[i][j] = fmaf(vf[i], xf[j], av[i][j]);
                }
        }
        __syncthreads();
    }

    const float scale = 0.0625f;  // 1/sqrt(256), folded into k only
    float* Kb = Kout + (size_t)b * C_DIM * N_DIM;
    float* Vb = Vout + (size_t)b * C_DIM * N_DIM;
    #pragma unroll
    for (int i = 0; i < 4; ++i) {
        int r = r0 + ty * 4 + i;
        float4 kq = make_float4(ak[i][0] * scale, ak[i][1] * scale,
                                ak[i][2] * scale, ak[i][3] * scale);
        float4 vq = make_float4(av[i][0], av[i][1], av[i][2], av[i][3]);
        *(float4*)(Kb + (size_t)r * N_DIM + n0 + tx * 4) = kq;
        *(float4*)(Vb + (size_t)r * N_DIM + n0 + tx * 4) = vq;
    }
}

// ---------------------------------------------------------------------------
// K2: banded scores. s[b,n,d] = sum_r (hidden[b,r,n]) * k_scaled[b,r,n+d],
// d in [-2,2].  denom[b,n] = N + sum_valid (exp(s)-1).
// Emits ew[b,n,dd] = (exp(s)-1)/denom   and   w[b,n] = 1/denom.
// Block = 320 threads = 64 n-positions x 5 diagonals; r staged in LDS chunks.
// ---------------------------------------------------------------------------
__global__ __launch_bounds__(320) void scores(
    const float* __restrict__ H,
    const float* __restrict__ K,
    float* __restrict__ EW,
    float* __restrict__ Wout)
{
    __shared__ float sh[64][64];
    __shared__ float sk[64][68];
    __shared__ float se[5][64];
    __shared__ float sw[64];

    const int b   = blockIdx.y;
    const int n0  = blockIdx.x * 64;
    const int tid = threadIdx.x;     // 0..319
    const int nl  = tid & 63;
    const int dd  = tid >> 6;        // 0..4  (d = dd-2)

    const float* Hb = H + (size_t)b * C_DIM * N_DIM;
    const float* Kb = K + (size_t)b * C_DIM * N_DIM;

    float acc = 0.f;
    for (int r0 = 0; r0 < C_DIM; r0 += 64) {
        for (int l = tid; l < 64 * 64; l += 320) {
            int r = l >> 6, n = l & 63;
            sh[r][n] = Hb[(size_t)(r0 + r) * N_DIM + n0 + n];
        }
        for (int l = tid; l < 64 * 68; l += 320) {
            int r = l / 68, n = l % 68;
            int gn = n0 + n - 2;
            sk[r][n] = (gn >= 0 && gn < N_DIM)
                     ? Kb[(size_t)(r0 + r) * N_DIM + gn] : 0.f;
        }
        __syncthreads();
        #pragma unroll 8
        for (int r = 0; r < 64; ++r)
            acc = fmaf(sh[r][nl], sk[r][nl + dd], acc);
        __syncthreads();
    }

    const int n = n0 + nl;
    const int m = n + dd - 2;                       // column index
    float e = (m >= 0 && m < N_DIM) ? (expf(acc) - 1.0f) : 0.f;
    se[dd][nl] = e;
    __syncthreads();
    if (tid < 64) {
        float denom = (float)N_DIM + se[0][tid] + se[1][tid] + se[2][tid]
                                   + se[3][tid] + se[4][tid];
        float wv = 1.0f / denom;
        sw[tid] = wv;
        Wout[(size_t)b * N_DIM + n0 + tid] = wv;
    }
    __syncthreads();
    EW[((size_t)b * N_DIM + n) * 5 + dd] = e * sw[nl];
}

// ---------------------------------------------------------------------------
// K3: rank-1 term. S[b,c] = sum_n v[b,c,n] * w[b,n]
// ---------------------------------------------------------------------------
__global__ __launch_bounds__(256) void colsum(
    const float* __restrict__ V,
    const float* __restrict__ Wn,
    float* __restrict__ S)
{
    const int c = blockIdx.x;
    const int b = blockIdx.y;
    const float* Vb = V  + ((size_t)b * C_DIM + c) * N_DIM;
    const float* wb = Wn + (size_t)b * N_DIM;
    float acc = 0.f;
    for (int n = threadIdx.x; n < N_DIM; n += 256)
        acc = fmaf(Vb[n], wb[n], acc);
    #pragma unroll
    for (int off = 32; off > 0; off >>= 1)
        acc += __shfl_down(acc, off, 64);
    __shared__ float sred[4];
    if ((threadIdx.x & 63) == 0) sred[threadIdx.x >> 6] = acc;
    __syncthreads();
    if (threadIdx.x == 0)
        S[(size_t)b * C_DIM + c] = sred[0] + sred[1] + sred[2] + sred[3];
}

// ---------------------------------------------------------------------------
// K4: epilogue. out[b,c,m] = x[b,c,m] + S[b,c]
//                          + sum_{d=-2..2} v[b,c,m+d] * ew[b, m+d, 2-d]
// (ew index: jj = (m-n)+2 = 4-dd with n = m+dd-2)
// ---------------------------------------------------------------------------
__global__ __launch_bounds__(256) void epilogue(
    const float* __restrict__ X,
    const float* __restrict__ V,
    const float* __restrict__ EW,
    const float* __restrict__ S,
    float* __restrict__ Out)
{
    size_t idx = (size_t)blockIdx.x * 256 + threadIdx.x;   // over B*C*N
    int    m   = (int)(idx & (N_DIM - 1));
    size_t bc  = idx >> 12;            // b*C + c
    int    b   = (int)(bc >> 8);

    float res = X[idx] + S[bc];
    const float* Vrow = V + (bc << 12);
    const float* ewb  = EW + (size_t)b * N_DIM * 5;
    #pragma unroll
    for (int dd = 0; dd < 5; ++dd) {
        int n = m + dd - 2;
        if (n >= 0 && n < N_DIM)
            res = fmaf(Vrow[n], ewb[(size_t)n * 5 + (4 - dd)], res);
    }
    Out[idx] = res;
}

// ---------------------------------------------------------------------------
extern "C" void kernel_launch(void* const* d_in, const int* in_sizes, int n_in,
                              void* d_out, int out_size, void* d_ws, size_t ws_size,
                              hipStream_t stream)
{
    const float* X  = (const float*)d_in[0];   // input  [B,C,N]
    const float* H  = (const float*)d_in[1];   // hidden [B,R,N]
    const float* Wk = (const float*)d_in[2];   // [R,C]
    const float* Wv = (const float*)d_in[3];   // [C,C]
    float* out = (float*)d_out;

    const size_t TENS = (size_t)B_DIM * C_DIM * N_DIM;   // 4194304
    float* k  = (float*)d_ws;
    float* v  = k  + TENS;
    float* ew = v  + TENS;                               // B*N*5
    float* w  = ew + (size_t)B_DIM * N_DIM * 5;          // B*N
    float* S  = w  + (size_t)B_DIM * N_DIM;              // B*C

    gemm_kv <<<dim3(N_DIM / 64, C_DIM / 64, B_DIM), 256, 0, stream>>>(X, Wk, Wv, k, v);
    scores  <<<dim3(N_DIM / 64, B_DIM),            320, 0, stream>>>(H, k, ew, w);
    colsum  <<<dim3(C_DIM, B_DIM),                 256, 0, stream>>>(v, w, S);
    epilogue<<<dim3((int)(TENS / 256)),            256, 0, stream>>>(X, v, ew, S, out);
}

// Round 2
// 160.784 us; speedup vs baseline: 1.2937x; 1.2937x over previous
//
#include <hip/hip_runtime.h>
#include <hip/hip_bf16.h>

#define B_DIM 4
#define C_DIM 256
#define N_DIM 4096

typedef unsigned short ushort8 __attribute__((ext_vector_type(8)));
typedef short          short8  __attribute__((ext_vector_type(8)));
typedef float          f32x4   __attribute__((ext_vector_type(4)));

__device__ __forceinline__ unsigned short f2bf(float x) {
    __hip_bfloat16 h = __float2bfloat16(x);
    return __builtin_bit_cast(unsigned short, h);
}
__device__ __forceinline__ float b2f(unsigned short u) {
    return __builtin_bit_cast(float, (unsigned)u << 16);
}

// ---------------------------------------------------------------------------
// castW: W fp32 [r][c] -> bf16 [r][c]; 1/sqrt(256) folded into Wk.
// ---------------------------------------------------------------------------
__global__ __launch_bounds__(256) void castW(
    const float* __restrict__ Wk, const float* __restrict__ Wv,
    unsigned short* __restrict__ Wkb, unsigned short* __restrict__ Wvb)
{
    const int mat = blockIdx.y;
    const float* src = mat ? Wv : Wk;
    unsigned short* dst = mat ? Wvb : Wkb;
    const float scale = mat ? 1.0f : 0.0625f;
    int idx = blockIdx.x * 2048 + threadIdx.x * 8;
    float4 f0 = *(const float4*)(src + idx);
    float4 f1 = *(const float4*)(src + idx + 4);
    ushort8 u;
    u[0] = f2bf(f0.x * scale); u[1] = f2bf(f0.y * scale);
    u[2] = f2bf(f0.z * scale); u[3] = f2bf(f0.w * scale);
    u[4] = f2bf(f1.x * scale); u[5] = f2bf(f1.y * scale);
    u[6] = f2bf(f1.z * scale); u[7] = f2bf(f1.w * scale);
    *(ushort8*)(dst + idx) = u;
}

// ---------------------------------------------------------------------------
// castX: X fp32 [b][c][n] -> XT bf16 [b][n][c]  (B-operand wants c contiguous)
// 64x64 transpose tiles through LDS.
// ---------------------------------------------------------------------------
__global__ __launch_bounds__(256) void castX(
    const float* __restrict__ X, unsigned short* __restrict__ XT)
{
    __shared__ float tile[64][65];
    const int n0 = blockIdx.x * 64, c0 = blockIdx.y * 64, b = blockIdx.z;
    const int tid = threadIdx.x;
    {
        int c = tid >> 2, ns = (tid & 3) * 16;
        const float* src = X + ((size_t)(b * C_DIM + c0 + c)) * N_DIM + n0 + ns;
        #pragma unroll
        for (int j = 0; j < 4; ++j) {
            float4 f = *(const float4*)(src + j * 4);
            tile[c][ns + j * 4 + 0] = f.x; tile[c][ns + j * 4 + 1] = f.y;
            tile[c][ns + j * 4 + 2] = f.z; tile[c][ns + j * 4 + 3] = f.w;
        }
    }
    __syncthreads();
    {
        int n = tid >> 2, cs = (tid & 3) * 16;
        ushort8 u0, u1;
        #pragma unroll
        for (int j = 0; j < 8; ++j) u0[j] = f2bf(tile[cs + j][n]);
        #pragma unroll
        for (int j = 0; j < 8; ++j) u1[j] = f2bf(tile[cs + 8 + j][n]);
        unsigned short* dst = XT + ((size_t)b * N_DIM + n0 + n) * C_DIM + c0 + cs;
        *(ushort8*)dst       = u0;
        *(ushort8*)(dst + 8) = u1;
    }
}

// ---------------------------------------------------------------------------
// gemm_mfma: D[r][n] = sum_c W[r][c] * X[c][n]  via bf16 MFMA 16x16x32.
// A-frag from W rows [r][c] (k contiguous), B-frag from XT rows [n][c].
// 128x128 tile / block, 4 waves each 64x64 (4x4 MFMA tiles), BK=32.
// blockIdx.z = b*2 + mat (mat 0 -> k, 1 -> v). Output bf16 [b][r][n].
// ---------------------------------------------------------------------------
__global__ __launch_bounds__(256) void gemm_mfma(
    const unsigned short* __restrict__ XT,
    const unsigned short* __restrict__ Wkb,
    const unsigned short* __restrict__ Wvb,
    unsigned short* __restrict__ Kout,
    unsigned short* __restrict__ Vout)
{
    __shared__ unsigned short sA[128][40];   // W tile  [r][c], +8 pad
    __shared__ unsigned short sB[128][40];   // XT tile [n][c], +8 pad

    const int bz  = blockIdx.z;
    const int b   = bz >> 1, mat = bz & 1;
    const int r0  = blockIdx.y * 128;
    const int n0  = blockIdx.x * 128;
    const int tid = threadIdx.x;
    const int lane = tid & 63, wid = tid >> 6;
    const int ln = lane & 15, q = lane >> 4;
    const int rw = wid >> 1, cw = wid & 1;

    const unsigned short* Wmat = mat ? Wvb : Wkb;
    const unsigned short* XTb  = XT + (size_t)b * N_DIM * C_DIM;

    f32x4 acc[4][4] = {};

    const int sr = tid >> 1;            // 0..127 staging row
    const int sh = (tid & 1) << 4;      // 0 / 16

    for (int c0 = 0; c0 < C_DIM; c0 += 32) {
        const unsigned short* ws = Wmat + (size_t)(r0 + sr) * C_DIM + c0 + sh;
        const unsigned short* xs = XTb + (size_t)(n0 + sr) * C_DIM + c0 + sh;
        ushort8 w0 = *(const ushort8*)ws;
        ushort8 w1 = *(const ushort8*)(ws + 8);
        ushort8 x0 = *(const ushort8*)xs;
        ushort8 x1 = *(const ushort8*)(xs + 8);
        *(ushort8*)&sA[sr][sh]     = w0;
        *(ushort8*)&sA[sr][sh + 8] = w1;
        *(ushort8*)&sB[sr][sh]     = x0;
        *(ushort8*)&sB[sr][sh + 8] = x1;
        __syncthreads();

        short8 a[4], bb[4];
        #pragma unroll
        for (int i = 0; i < 4; ++i)
            a[i] = *(const short8*)&sA[rw * 64 + i * 16 + ln][q * 8];
        #pragma unroll
        for (int j = 0; j < 4; ++j)
            bb[j] = *(const short8*)&sB[cw * 64 + j * 16 + ln][q * 8];
        #pragma unroll
        for (int i = 0; i < 4; ++i)
            #pragma unroll
            for (int j = 0; j < 4; ++j)
                acc[i][j] = __builtin_amdgcn_mfma_f32_16x16x32_bf16(
                    a[i], bb[j], acc[i][j], 0, 0, 0);
        __syncthreads();
    }

    unsigned short* O = (mat ? Vout : Kout) + (size_t)b * C_DIM * N_DIM;
    #pragma unroll
    for (int i = 0; i < 4; ++i)
        #pragma unroll
        for (int reg = 0; reg < 4; ++reg) {
            int r = r0 + rw * 64 + i * 16 + q * 4 + reg;
            size_t base = (size_t)r * N_DIM + n0 + cw * 64 + ln;
            #pragma unroll
            for (int j = 0; j < 4; ++j)
                O[base + j * 16] = f2bf(acc[i][j][reg]);
        }
}

// ---------------------------------------------------------------------------
// scores: s[b,n,d] = sum_r H[b,r,n] * k[b,r,n+d-2]   (k pre-scaled, bf16)
// denom[n] = N + sum_valid (exp(s)-1);  EW plane layout [b][dd][n] = e/denom;
// Wout[b][n] = 1/denom.  Block = 320 thr = 64 n x 5 diagonals.
// ---------------------------------------------------------------------------
__global__ __launch_bounds__(320) void scores(
    const float* __restrict__ H,
    const unsigned short* __restrict__ K,
    float* __restrict__ EW,
    float* __restrict__ Wout)
{
    __shared__ float shm[64][64];
    __shared__ float skm[64][68];
    __shared__ float se[5][64];
    __shared__ float sw[64];

    const int b   = blockIdx.y;
    const int n0  = blockIdx.x * 64;
    const int tid = threadIdx.x;
    const int nl  = tid & 63;
    const int dd  = tid >> 6;

    const float* Hb = H + (size_t)b * C_DIM * N_DIM;
    const unsigned short* Kb = K + (size_t)b * C_DIM * N_DIM;

    float acc = 0.f;
    for (int r0 = 0; r0 < C_DIM; r0 += 64) {
        for (int l = tid; l < 64 * 64; l += 320) {
            int r = l >> 6, n = l & 63;
            shm[r][n] = Hb[(size_t)(r0 + r) * N_DIM + n0 + n];
        }
        for (int l = tid; l < 64 * 68; l += 320) {
            int r = l / 68, n = l % 68;
            int gn = n0 + n - 2;
            skm[r][n] = (gn >= 0 && gn < N_DIM)
                      ? b2f(Kb[(size_t)(r0 + r) * N_DIM + gn]) : 0.f;
        }
        __syncthreads();
        #pragma unroll 8
        for (int r = 0; r < 64; ++r)
            acc = fmaf(shm[r][nl], skm[r][nl + dd], acc);
        __syncthreads();
    }

    const int n = n0 + nl;
    const int m = n + dd - 2;
    float e = (m >= 0 && m < N_DIM) ? (expf(acc) - 1.0f) : 0.f;
    se[dd][nl] = e;
    __syncthreads();
    if (tid < 64) {
        float denom = (float)N_DIM + se[0][tid] + se[1][tid] + se[2][tid]
                                   + se[3][tid] + se[4][tid];
        float wv = 1.0f / denom;
        sw[tid] = wv;
        Wout[(size_t)b * N_DIM + n0 + tid] = wv;
    }
    __syncthreads();
    EW[((size_t)b * 5 + dd) * N_DIM + n] = e * sw[nl];
}

// ---------------------------------------------------------------------------
// epi: fused colsum + epilogue.  One block per (b,c) row.
//  S = sum_n v[n]*w[n] (v staged to LDS while reducing), then
//  out[m] = x[m] + S + sum_{dd} v[m+dd-2] * EW[b][4-dd][m+dd-2]
// ---------------------------------------------------------------------------
__global__ __launch_bounds__(256) void epi(
    const float* __restrict__ X,
    const unsigned short* __restrict__ V,
    const float* __restrict__ EW,
    const float* __restrict__ Wn,
    float* __restrict__ Out)
{
    __shared__ unsigned short sv[N_DIM];
    __shared__ float sred[4];

    const int c = blockIdx.x, b = blockIdx.y;
    const int tid = threadIdx.x, lane = tid & 63, wid = tid >> 6;
    const size_t row = (size_t)b * C_DIM + c;

    const ushort8* v8   = (const ushort8*)(V + row * N_DIM);
    const float*   wrow = Wn + (size_t)b * N_DIM;

    float acc = 0.f;
    #pragma unroll
    for (int it = 0; it < 2; ++it) {
        int i = tid + it * 256;                 // chunk of 8
        ushort8 u = v8[i];
        *(ushort8*)&sv[i * 8] = u;
        const float4 w0 = *(const float4*)(wrow + i * 8);
        const float4 w1 = *(const float4*)(wrow + i * 8 + 4);
        acc += b2f(u[0]) * w0.x + b2f(u[1]) * w0.y
             + b2f(u[2]) * w0.z + b2f(u[3]) * w0.w
             + b2f(u[4]) * w1.x + b2f(u[5]) * w1.y
             + b2f(u[6]) * w1.z + b2f(u[7]) * w1.w;
    }
    #pragma unroll
    for (int off = 32; off > 0; off >>= 1)
        acc += __shfl_down(acc, off, 64);
    if (lane == 0) sred[wid] = acc;
    __syncthreads();
    const float S = sred[0] + sred[1] + sred[2] + sred[3];

    const float* xrow = X + row * N_DIM;
    float*       orow = Out + row * N_DIM;
    const float* ewb  = EW + (size_t)b * 5 * N_DIM;
    for (int m = tid; m < N_DIM; m += 256) {
        float res = xrow[m] + S;
        #pragma unroll
        for (int dd = 0; dd < 5; ++dd) {
            int n = m + dd - 2;
            if (n >= 0 && n < N_DIM)
                res = fmaf(b2f(sv[n]), ewb[(size_t)(4 - dd) * N_DIM + n], res);
        }
        orow[m] = res;
    }
}

// ---------------------------------------------------------------------------
extern "C" void kernel_launch(void* const* d_in, const int* in_sizes, int n_in,
                              void* d_out, int out_size, void* d_ws, size_t ws_size,
                              hipStream_t stream)
{
    const float* X  = (const float*)d_in[0];   // [B,C,N]
    const float* H  = (const float*)d_in[1];   // [B,R,N]
    const float* Wk = (const float*)d_in[2];   // [R,C]
    const float* Wv = (const float*)d_in[3];   // [C,C]
    float* out = (float*)d_out;

    const size_t TENS = (size_t)B_DIM * C_DIM * N_DIM;   // 4194304
    unsigned short* XT  = (unsigned short*)d_ws;         // bf16 [b][n][c]
    unsigned short* Wkb = XT  + TENS;                    // 65536
    unsigned short* Wvb = Wkb + 65536;
    unsigned short* Kb  = Wvb + 65536;                   // bf16 [b][r][n]
    unsigned short* Vb  = Kb  + TENS;
    float* EW = (float*)(Vb + TENS);                     // [b][5][n]
    float* Wn = EW + (size_t)B_DIM * 5 * N_DIM;          // [b][n]

    castW<<<dim3(32, 2),                       256, 0, stream>>>(Wk, Wv, Wkb, Wvb);
    castX<<<dim3(N_DIM / 64, C_DIM / 64, B_DIM), 256, 0, stream>>>(X, XT);
    gemm_mfma<<<dim3(N_DIM / 128, C_DIM / 128, B_DIM * 2), 256, 0, stream>>>(
        XT, Wkb, Wvb, Kb, Vb);
    scores<<<dim3(N_DIM / 64, B_DIM),          320, 0, stream>>>(H, Kb, EW, Wn);
    epi<<<dim3(C_DIM, B_DIM),                  256, 0, stream>>>(X, Vb, EW, Wn, out);
}

// Round 3
// 139.746 us; speedup vs baseline: 1.4885x; 1.1505x over previous
//
#include <hip/hip_runtime.h>
#include <hip/hip_bf16.h>

#define B_DIM 4
#define C_DIM 256
#define N_DIM 4096

typedef unsigned short ushort8 __attribute__((ext_vector_type(8)));
typedef short          short8  __attribute__((ext_vector_type(8)));
typedef float          f32x4   __attribute__((ext_vector_type(4)));

__device__ __forceinline__ unsigned short f2bf(float x) {
    __hip_bfloat16 h = __float2bfloat16(x);
    return __builtin_bit_cast(unsigned short, h);
}
__device__ __forceinline__ float b2f(unsigned short u) {
    return __builtin_bit_cast(float, (unsigned)u << 16);
}

// ---------------------------------------------------------------------------
// castW: W fp32 [r][c] -> bf16 [r][c]; 1/sqrt(256) folded into Wk.
// ---------------------------------------------------------------------------
__global__ __launch_bounds__(256) void castW(
    const float* __restrict__ Wk, const float* __restrict__ Wv,
    unsigned short* __restrict__ Wkb, unsigned short* __restrict__ Wvb)
{
    const int mat = blockIdx.y;
    const float* src = mat ? Wv : Wk;
    unsigned short* dst = mat ? Wvb : Wkb;
    const float scale = mat ? 1.0f : 0.0625f;
    int idx = blockIdx.x * 2048 + threadIdx.x * 8;
    float4 f0 = *(const float4*)(src + idx);
    float4 f1 = *(const float4*)(src + idx + 4);
    ushort8 u;
    u[0] = f2bf(f0.x * scale); u[1] = f2bf(f0.y * scale);
    u[2] = f2bf(f0.z * scale); u[3] = f2bf(f0.w * scale);
    u[4] = f2bf(f1.x * scale); u[5] = f2bf(f1.y * scale);
    u[6] = f2bf(f1.z * scale); u[7] = f2bf(f1.w * scale);
    *(ushort8*)(dst + idx) = u;
}

// ---------------------------------------------------------------------------
// castX: X fp32 [b][c][n] -> XT bf16 [b][n][c]  (B-operand wants c contiguous)
// 64x64 transpose tiles through LDS.
// ---------------------------------------------------------------------------
__global__ __launch_bounds__(256) void castX(
    const float* __restrict__ X, unsigned short* __restrict__ XT)
{
    __shared__ float tile[64][65];
    const int n0 = blockIdx.x * 64, c0 = blockIdx.y * 64, b = blockIdx.z;
    const int tid = threadIdx.x;
    {
        int c = tid >> 2, ns = (tid & 3) * 16;
        const float* src = X + ((size_t)(b * C_DIM + c0 + c)) * N_DIM + n0 + ns;
        #pragma unroll
        for (int j = 0; j < 4; ++j) {
            float4 f = *(const float4*)(src + j * 4);
            tile[c][ns + j * 4 + 0] = f.x; tile[c][ns + j * 4 + 1] = f.y;
            tile[c][ns + j * 4 + 2] = f.z; tile[c][ns + j * 4 + 3] = f.w;
        }
    }
    __syncthreads();
    {
        int n = tid >> 2, cs = (tid & 3) * 16;
        ushort8 u0, u1;
        #pragma unroll
        for (int j = 0; j < 8; ++j) u0[j] = f2bf(tile[cs + j][n]);
        #pragma unroll
        for (int j = 0; j < 8; ++j) u1[j] = f2bf(tile[cs + 8 + j][n]);
        unsigned short* dst = XT + ((size_t)b * N_DIM + n0 + n) * C_DIM + c0 + cs;
        *(ushort8*)dst       = u0;
        *(ushort8*)(dst + 8) = u1;
    }
}

// ---------------------------------------------------------------------------
// gemm_mfma: D[r][n] = sum_c W[r][c] * X[c][n]  via bf16 MFMA 16x16x32.
// 128x128 tile / block, 4 waves each 64x64 (4x4 MFMA tiles), BK=32.
// blockIdx.z = b*2 + mat (mat 0 -> k, 1 -> v). Output bf16 [b][r][n].
// ---------------------------------------------------------------------------
__global__ __launch_bounds__(256) void gemm_mfma(
    const unsigned short* __restrict__ XT,
    const unsigned short* __restrict__ Wkb,
    const unsigned short* __restrict__ Wvb,
    unsigned short* __restrict__ Kout,
    unsigned short* __restrict__ Vout)
{
    __shared__ unsigned short sA[128][40];   // W tile  [r][c], +8 pad
    __shared__ unsigned short sB[128][40];   // XT tile [n][c], +8 pad

    const int bz  = blockIdx.z;
    const int b   = bz >> 1, mat = bz & 1;
    const int r0  = blockIdx.y * 128;
    const int n0  = blockIdx.x * 128;
    const int tid = threadIdx.x;
    const int lane = tid & 63, wid = tid >> 6;
    const int ln = lane & 15, q = lane >> 4;
    const int rw = wid >> 1, cw = wid & 1;

    const unsigned short* Wmat = mat ? Wvb : Wkb;
    const unsigned short* XTb  = XT + (size_t)b * N_DIM * C_DIM;

    f32x4 acc[4][4] = {};

    const int sr = tid >> 1;            // 0..127 staging row
    const int sh = (tid & 1) << 4;      // 0 / 16

    for (int c0 = 0; c0 < C_DIM; c0 += 32) {
        const unsigned short* ws = Wmat + (size_t)(r0 + sr) * C_DIM + c0 + sh;
        const unsigned short* xs = XTb + (size_t)(n0 + sr) * C_DIM + c0 + sh;
        ushort8 w0 = *(const ushort8*)ws;
        ushort8 w1 = *(const ushort8*)(ws + 8);
        ushort8 x0 = *(const ushort8*)xs;
        ushort8 x1 = *(const ushort8*)(xs + 8);
        *(ushort8*)&sA[sr][sh]     = w0;
        *(ushort8*)&sA[sr][sh + 8] = w1;
        *(ushort8*)&sB[sr][sh]     = x0;
        *(ushort8*)&sB[sr][sh + 8] = x1;
        __syncthreads();

        short8 a[4], bb[4];
        #pragma unroll
        for (int i = 0; i < 4; ++i)
            a[i] = *(const short8*)&sA[rw * 64 + i * 16 + ln][q * 8];
        #pragma unroll
        for (int j = 0; j < 4; ++j)
            bb[j] = *(const short8*)&sB[cw * 64 + j * 16 + ln][q * 8];
        #pragma unroll
        for (int i = 0; i < 4; ++i)
            #pragma unroll
            for (int j = 0; j < 4; ++j)
                acc[i][j] = __builtin_amdgcn_mfma_f32_16x16x32_bf16(
                    a[i], bb[j], acc[i][j], 0, 0, 0);
        __syncthreads();
    }

    unsigned short* O = (mat ? Vout : Kout) + (size_t)b * C_DIM * N_DIM;
    #pragma unroll
    for (int i = 0; i < 4; ++i)
        #pragma unroll
        for (int reg = 0; reg < 4; ++reg) {
            int r = r0 + rw * 64 + i * 16 + q * 4 + reg;
            size_t base = (size_t)r * N_DIM + n0 + cw * 64 + ln;
            #pragma unroll
            for (int j = 0; j < 4; ++j)
                O[base + j * 16] = f2bf(acc[i][j][reg]);
        }
}

// ---------------------------------------------------------------------------
// scores: s[b,n,dd] = sum_r H[b,r,n] * k[b,r,n+dd-2]   (k pre-scaled, bf16)
// Latency-optimized: block = 512 thr = 32 n-positions x 16 r-chunks of 16.
// Direct global loads (no LDS staging of H/K), LDS tree-reduce over chunks.
// denom[n] = N + sum_valid (exp(s)-1); EW[b][dd][n] = e/denom; Wout = 1/denom.
// ---------------------------------------------------------------------------
__global__ __launch_bounds__(512) void scores(
    const float* __restrict__ H,
    const unsigned short* __restrict__ K,
    float* __restrict__ EW,
    float* __restrict__ Wout)
{
    __shared__ float sacc[16][5][32];
    __shared__ float se[5][32];
    __shared__ float sw[32];

    const int b   = blockIdx.y;
    const int n0  = blockIdx.x * 32;
    const int tid = threadIdx.x;
    const int nl  = tid & 31;
    const int ch  = tid >> 5;          // 0..15 (r-chunk)
    const int n   = n0 + nl;

    const float* Hb = H + ((size_t)b * C_DIM + ch * 16) * N_DIM + n;
    const unsigned short* Kb = K + ((size_t)b * C_DIM + ch * 16) * N_DIM;

    // fixed, clamped column indices (edge garbage discarded via e=0 below)
    int m[5];
    #pragma unroll
    for (int dd = 0; dd < 5; ++dd) {
        int mm = n + dd - 2;
        m[dd] = mm < 0 ? 0 : (mm >= N_DIM ? N_DIM - 1 : mm);
    }

    float acc[5] = {0.f, 0.f, 0.f, 0.f, 0.f};
    #pragma unroll 8
    for (int r = 0; r < 16; ++r) {
        float hv = Hb[(size_t)r * N_DIM];
        const unsigned short* kr = Kb + (size_t)r * N_DIM;
        #pragma unroll
        for (int dd = 0; dd < 5; ++dd)
            acc[dd] = fmaf(hv, b2f(kr[m[dd]]), acc[dd]);
    }
    #pragma unroll
    for (int dd = 0; dd < 5; ++dd) sacc[ch][dd][nl] = acc[dd];
    __syncthreads();

    if (tid < 160) {
        const int dd = tid >> 5, nn = tid & 31;
        float s = 0.f;
        #pragma unroll
        for (int c = 0; c < 16; ++c) s += sacc[c][dd][nn];
        const int mm = n0 + nn + dd - 2;
        se[dd][nn] = (mm >= 0 && mm < N_DIM) ? expf(s) - 1.0f : 0.f;
    }
    __syncthreads();
    if (tid < 32) {
        float denom = (float)N_DIM + se[0][tid] + se[1][tid] + se[2][tid]
                                   + se[3][tid] + se[4][tid];
        float wv = 1.0f / denom;
        sw[tid] = wv;
        Wout[(size_t)b * N_DIM + n0 + tid] = wv;
    }
    __syncthreads();
    if (tid < 160) {
        const int dd = tid >> 5, nn = tid & 31;
        EW[((size_t)b * 5 + dd) * N_DIM + n0 + nn] = se[dd][nn] * sw[nn];
    }
}

// ---------------------------------------------------------------------------
// epi: fused colsum + epilogue.  One block per (b,c) row.
//  S = sum_n v[n]*w[n] (v staged to LDS while reducing), then
//  out[m] = x[m] + S + sum_{dd} v[m+dd-2] * EW[b][4-dd][m+dd-2]
// ---------------------------------------------------------------------------
__global__ __launch_bounds__(256) void epi(
    const float* __restrict__ X,
    const unsigned short* __restrict__ V,
    const float* __restrict__ EW,
    const float* __restrict__ Wn,
    float* __restrict__ Out)
{
    __shared__ unsigned short sv[N_DIM];
    __shared__ float sred[4];

    const int c = blockIdx.x, b = blockIdx.y;
    const int tid = threadIdx.x, lane = tid & 63, wid = tid >> 6;
    const size_t row = (size_t)b * C_DIM + c;

    const ushort8* v8   = (const ushort8*)(V + row * N_DIM);
    const float*   wrow = Wn + (size_t)b * N_DIM;

    float acc = 0.f;
    #pragma unroll
    for (int it = 0; it < 2; ++it) {
        int i = tid + it * 256;                 // chunk of 8
        ushort8 u = v8[i];
        *(ushort8*)&sv[i * 8] = u;
        const float4 w0 = *(const float4*)(wrow + i * 8);
        const float4 w1 = *(const float4*)(wrow + i * 8 + 4);
        acc += b2f(u[0]) * w0.x + b2f(u[1]) * w0.y
             + b2f(u[2]) * w0.z + b2f(u[3]) * w0.w
             + b2f(u[4]) * w1.x + b2f(u[5]) * w1.y
             + b2f(u[6]) * w1.z + b2f(u[7]) * w1.w;
    }
    #pragma unroll
    for (int off = 32; off > 0; off >>= 1)
        acc += __shfl_down(acc, off, 64);
    if (lane == 0) sred[wid] = acc;
    __syncthreads();
    const float S = sred[0] + sred[1] + sred[2] + sred[3];

    const float* xrow = X + row * N_DIM;
    float*       orow = Out + row * N_DIM;
    const float* ewb  = EW + (size_t)b * 5 * N_DIM;
    for (int m = tid; m < N_DIM; m += 256) {
        float res = xrow[m] + S;
        #pragma unroll
        for (int dd = 0; dd < 5; ++dd) {
            int n = m + dd - 2;
            if (n >= 0 && n < N_DIM)
                res = fmaf(b2f(sv[n]), ewb[(size_t)(4 - dd) * N_DIM + n], res);
        }
        orow[m] = res;
    }
}

// ---------------------------------------------------------------------------
extern "C" void kernel_launch(void* const* d_in, const int* in_sizes, int n_in,
                              void* d_out, int out_size, void* d_ws, size_t ws_size,
                              hipStream_t stream)
{
    const float* X  = (const float*)d_in[0];   // [B,C,N]
    const float* H  = (const float*)d_in[1];   // [B,R,N]
    const float* Wk = (const float*)d_in[2];   // [R,C]
    const float* Wv = (const float*)d_in[3];   // [C,C]
    float* out = (float*)d_out;

    const size_t TENS = (size_t)B_DIM * C_DIM * N_DIM;   // 4194304
    unsigned short* XT  = (unsigned short*)d_ws;         // bf16 [b][n][c]
    unsigned short* Wkb = XT  + TENS;                    // 65536
    unsigned short* Wvb = Wkb + 65536;
    unsigned short* Kb  = Wvb + 65536;                   // bf16 [b][r][n]
    unsigned short* Vb  = Kb  + TENS;
    float* EW = (float*)(Vb + TENS);                     // [b][5][n]
    float* Wn = EW + (size_t)B_DIM * 5 * N_DIM;          // [b][n]

    castW<<<dim3(32, 2),                       256, 0, stream>>>(Wk, Wv, Wkb, Wvb);
    castX<<<dim3(N_DIM / 64, C_DIM / 64, B_DIM), 256, 0, stream>>>(X, XT);
    gemm_mfma<<<dim3(N_DIM / 128, C_DIM / 128, B_DIM * 2), 256, 0, stream>>>(
        XT, Wkb, Wvb, Kb, Vb);
    scores<<<dim3(N_DIM / 32, B_DIM),          512, 0, stream>>>(H, Kb, EW, Wn);
    epi<<<dim3(C_DIM, B_DIM),                  256, 0, stream>>>(X, Vb, EW, Wn, out);
}

// Round 4
// 128.151 us; speedup vs baseline: 1.6232x; 1.0905x over previous
//
#include <hip/hip_runtime.h>
#include <hip/hip_bf16.h>

#define B_DIM 4
#define C_DIM 256
#define N_DIM 4096

typedef unsigned short ushort8 __attribute__((ext_vector_type(8)));
typedef unsigned short ushort4v __attribute__((ext_vector_type(4)));
typedef short          short8  __attribute__((ext_vector_type(8)));
typedef float          f32x4   __attribute__((ext_vector_type(4)));

__device__ __forceinline__ unsigned short f2bf(float x) {
    __hip_bfloat16 h = __float2bfloat16(x);
    return __builtin_bit_cast(unsigned short, h);
}
__device__ __forceinline__ float b2f(unsigned short u) {
    return __builtin_bit_cast(float, (unsigned)u << 16);
}

// ---------------------------------------------------------------------------
// castW: W fp32 [r][c] -> bf16 [r][c]; 1/sqrt(256) folded into Wk.
// ---------------------------------------------------------------------------
__global__ __launch_bounds__(256) void castW(
    const float* __restrict__ Wk, const float* __restrict__ Wv,
    unsigned short* __restrict__ Wkb, unsigned short* __restrict__ Wvb)
{
    const int mat = blockIdx.y;
    const float* src = mat ? Wv : Wk;
    unsigned short* dst = mat ? Wvb : Wkb;
    const float scale = mat ? 1.0f : 0.0625f;
    int idx = blockIdx.x * 2048 + threadIdx.x * 8;
    float4 f0 = *(const float4*)(src + idx);
    float4 f1 = *(const float4*)(src + idx + 4);
    ushort8 u;
    u[0] = f2bf(f0.x * scale); u[1] = f2bf(f0.y * scale);
    u[2] = f2bf(f0.z * scale); u[3] = f2bf(f0.w * scale);
    u[4] = f2bf(f1.x * scale); u[5] = f2bf(f1.y * scale);
    u[6] = f2bf(f1.z * scale); u[7] = f2bf(f1.w * scale);
    *(ushort8*)(dst + idx) = u;
}

// ---------------------------------------------------------------------------
// castX: X fp32 [b][c][n] -> XT bf16 [b][n][c]  (B-operand wants c contiguous)
// ---------------------------------------------------------------------------
__global__ __launch_bounds__(256) void castX(
    const float* __restrict__ X, unsigned short* __restrict__ XT)
{
    __shared__ float tile[64][65];
    const int n0 = blockIdx.x * 64, c0 = blockIdx.y * 64, b = blockIdx.z;
    const int tid = threadIdx.x;
    {
        int c = tid >> 2, ns = (tid & 3) * 16;
        const float* src = X + ((size_t)(b * C_DIM + c0 + c)) * N_DIM + n0 + ns;
        #pragma unroll
        for (int j = 0; j < 4; ++j) {
            float4 f = *(const float4*)(src + j * 4);
            tile[c][ns + j * 4 + 0] = f.x; tile[c][ns + j * 4 + 1] = f.y;
            tile[c][ns + j * 4 + 2] = f.z; tile[c][ns + j * 4 + 3] = f.w;
        }
    }
    __syncthreads();
    {
        int n = tid >> 2, cs = (tid & 3) * 16;
        ushort8 u0, u1;
        #pragma unroll
        for (int j = 0; j < 8; ++j) u0[j] = f2bf(tile[cs + j][n]);
        #pragma unroll
        for (int j = 0; j < 8; ++j) u1[j] = f2bf(tile[cs + 8 + j][n]);
        unsigned short* dst = XT + ((size_t)b * N_DIM + n0 + n) * C_DIM + c0 + cs;
        *(ushort8*)dst       = u0;
        *(ushort8*)(dst + 8) = u1;
    }
}

// ---------------------------------------------------------------------------
// gemm_kv: LDS-free fused k+v GEMM via bf16 MFMA 16x16x32.
// Block = 256 thr = 4 waves; tile 128n x 64r, BOTH mats.  Wave = 64n x 32r.
// A-frags (W rows, k-contig) and B-frags (XT rows, k-contig) loaded as
// 16B global loads straight into MFMA fragments.  No LDS, no barriers.
// ---------------------------------------------------------------------------
__global__ __launch_bounds__(256) void gemm_kv(
    const unsigned short* __restrict__ XT,
    const unsigned short* __restrict__ Wkb,
    const unsigned short* __restrict__ Wvb,
    unsigned short* __restrict__ Kout,
    unsigned short* __restrict__ Vout)
{
    const int b  = blockIdx.z;
    const int r0 = blockIdx.y * 64;
    const int n0 = blockIdx.x * 128;
    const int tid = threadIdx.x, lane = tid & 63, wid = tid >> 6;
    const int ln = lane & 15, q = lane >> 4;
    const int cw = wid & 1, rw = wid >> 1;
    const int rbase = r0 + rw * 32;
    const int nbase = n0 + cw * 64;

    const unsigned short* XTb = XT + (size_t)b * N_DIM * C_DIM;

    const unsigned short* pa0 = Wkb + (size_t)(rbase + ln) * C_DIM + q * 8;
    const unsigned short* pa1 = pa0 + 16 * C_DIM;
    const unsigned short* pv0 = Wvb + (size_t)(rbase + ln) * C_DIM + q * 8;
    const unsigned short* pv1 = pv0 + 16 * C_DIM;
    const unsigned short* pb0 = XTb + (size_t)(nbase + ln) * C_DIM + q * 8;
    const unsigned short* pb1 = pb0 + 16 * C_DIM;
    const unsigned short* pb2 = pb0 + 32 * C_DIM;
    const unsigned short* pb3 = pb0 + 48 * C_DIM;

    f32x4 ak[2][4] = {};
    f32x4 av[2][4] = {};

    #pragma unroll
    for (int c0 = 0; c0 < C_DIM; c0 += 32) {
        short8 A0 = *(const short8*)(pa0 + c0);
        short8 A1 = *(const short8*)(pa1 + c0);
        short8 V0 = *(const short8*)(pv0 + c0);
        short8 V1 = *(const short8*)(pv1 + c0);
        short8 Bf[4];
        Bf[0] = *(const short8*)(pb0 + c0);
        Bf[1] = *(const short8*)(pb1 + c0);
        Bf[2] = *(const short8*)(pb2 + c0);
        Bf[3] = *(const short8*)(pb3 + c0);
        #pragma unroll
        for (int j = 0; j < 4; ++j) {
            ak[0][j] = __builtin_amdgcn_mfma_f32_16x16x32_bf16(A0, Bf[j], ak[0][j], 0, 0, 0);
            ak[1][j] = __builtin_amdgcn_mfma_f32_16x16x32_bf16(A1, Bf[j], ak[1][j], 0, 0, 0);
            av[0][j] = __builtin_amdgcn_mfma_f32_16x16x32_bf16(V0, Bf[j], av[0][j], 0, 0, 0);
            av[1][j] = __builtin_amdgcn_mfma_f32_16x16x32_bf16(V1, Bf[j], av[1][j], 0, 0, 0);
        }
    }

    unsigned short* Kb = Kout + (size_t)b * C_DIM * N_DIM;
    unsigned short* Vb = Vout + (size_t)b * C_DIM * N_DIM;
    #pragma unroll
    for (int i = 0; i < 2; ++i)
        #pragma unroll
        for (int reg = 0; reg < 4; ++reg) {
            int r = rbase + i * 16 + q * 4 + reg;
            size_t base = (size_t)r * N_DIM + nbase + ln;
            #pragma unroll
            for (int j = 0; j < 4; ++j) {
                Kb[base + j * 16] = f2bf(ak[i][j][reg]);
                Vb[base + j * 16] = f2bf(av[i][j][reg]);
            }
        }
}

// ---------------------------------------------------------------------------
// scores: s[b,n,dd] = sum_r H[b,r,n] * k[b,r,n+dd-2]   (k pre-scaled, bf16)
// Block = 512 thr = 32 n x 16 r-chunks, direct global loads, LDS tree-reduce.
// Emits EWT[b][ddp][m] (band weights indexed by OUTPUT column m, so the
// epilogue can read them as coalesced float4) and Wout[b][n] = 1/denom.
//   EWT[4-dd][n+dd-2] = (exp(s[n,dd])-1)/denom[n]
// ---------------------------------------------------------------------------
__global__ __launch_bounds__(512) void scores(
    const float* __restrict__ H,
    const unsigned short* __restrict__ K,
    float* __restrict__ EWT,
    float* __restrict__ Wout)
{
    __shared__ float sacc[16][5][32];
    __shared__ float se[5][32];
    __shared__ float sw[32];

    const int b   = blockIdx.y;
    const int n0  = blockIdx.x * 32;
    const int tid = threadIdx.x;
    const int nl  = tid & 31;
    const int ch  = tid >> 5;          // 0..15 (r-chunk)
    const int n   = n0 + nl;

    const float* Hb = H + ((size_t)b * C_DIM + ch * 16) * N_DIM + n;
    const unsigned short* Kb = K + ((size_t)b * C_DIM + ch * 16) * N_DIM;

    int m[5];
    #pragma unroll
    for (int dd = 0; dd < 5; ++dd) {
        int mm = n + dd - 2;
        m[dd] = mm < 0 ? 0 : (mm >= N_DIM ? N_DIM - 1 : mm);
    }

    float acc[5] = {0.f, 0.f, 0.f, 0.f, 0.f};
    #pragma unroll 8
    for (int r = 0; r < 16; ++r) {
        float hv = Hb[(size_t)r * N_DIM];
        const unsigned short* kr = Kb + (size_t)r * N_DIM;
        #pragma unroll
        for (int dd = 0; dd < 5; ++dd)
            acc[dd] = fmaf(hv, b2f(kr[m[dd]]), acc[dd]);
    }
    #pragma unroll
    for (int dd = 0; dd < 5; ++dd) sacc[ch][dd][nl] = acc[dd];
    __syncthreads();

    if (tid < 160) {
        const int dd = tid >> 5, nn = tid & 31;
        float s = 0.f;
        #pragma unroll
        for (int c = 0; c < 16; ++c) s += sacc[c][dd][nn];
        const int mm = n0 + nn + dd - 2;
        se[dd][nn] = (mm >= 0 && mm < N_DIM) ? expf(s) - 1.0f : 0.f;
    }
    __syncthreads();
    if (tid < 32) {
        float denom = (float)N_DIM + se[0][tid] + se[1][tid] + se[2][tid]
                                   + se[3][tid] + se[4][tid];
        float wv = 1.0f / denom;
        sw[tid] = wv;
        Wout[(size_t)b * N_DIM + n0 + tid] = wv;
    }
    __syncthreads();
    if (tid < 160) {
        const int dd = tid >> 5, nn = tid & 31;
        const int nn_g = n0 + nn;
        const int mm = nn_g + dd - 2;                 // output column
        if (mm >= 0 && mm < N_DIM)
            EWT[((size_t)b * 5 + (4 - dd)) * N_DIM + mm] = se[dd][nn] * sw[nn];
    }
}

// ---------------------------------------------------------------------------
// epi: fused colsum + epilogue, fully vectorized.  One block per (b,c) row.
//  S = sum_n v[n]*w[n]  (v staged into zero-padded LDS while reducing), then
//  out[m] = x[m] + S + sum_{dd=0..4} v[m+dd-2] * EWT[b][dd][m]
// Zero padding of sv makes all edge products exactly 0 -> no branches; the
// few EWT cells never written by scores are always multiplied by padded 0.
// ---------------------------------------------------------------------------
__global__ __launch_bounds__(256) void epi(
    const float* __restrict__ X,
    const unsigned short* __restrict__ V,
    const float* __restrict__ EWT,
    const float* __restrict__ Wn,
    float* __restrict__ Out)
{
    __shared__ unsigned short sv[N_DIM + 8];   // [0..3]=0, v at +4, tail 0
    __shared__ float sred[4];

    const int c = blockIdx.x, b = blockIdx.y;
    const int tid = threadIdx.x, lane = tid & 63, wid = tid >> 6;
    const size_t row = (size_t)b * C_DIM + c;

    if (tid < 4) { sv[tid] = 0; sv[N_DIM + 4 + tid] = 0; }

    const ushort8* v8   = (const ushort8*)(V + row * N_DIM);
    const float*   wrow = Wn + (size_t)b * N_DIM;

    float acc = 0.f;
    #pragma unroll
    for (int it = 0; it < 2; ++it) {
        int i = tid + it * 256;                 // chunk of 8
        ushort8 u = v8[i];
        *(ushort4v*)&sv[4 + i * 8]     = ushort4v{u[0], u[1], u[2], u[3]};
        *(ushort4v*)&sv[4 + i * 8 + 4] = ushort4v{u[4], u[5], u[6], u[7]};
        const float4 w0 = *(const float4*)(wrow + i * 8);
        const float4 w1 = *(const float4*)(wrow + i * 8 + 4);
        acc += b2f(u[0]) * w0.x + b2f(u[1]) * w0.y
             + b2f(u[2]) * w0.z + b2f(u[3]) * w0.w
             + b2f(u[4]) * w1.x + b2f(u[5]) * w1.y
             + b2f(u[6]) * w1.z + b2f(u[7]) * w1.w;
    }
    #pragma unroll
    for (int off = 32; off > 0; off >>= 1)
        acc += __shfl_down(acc, off, 64);
    if (lane == 0) sred[wid] = acc;
    __syncthreads();
    const float S = sred[0] + sred[1] + sred[2] + sred[3];

    const float* xrow = X + row * N_DIM;
    float*       orow = Out + row * N_DIM;
    const float* ewt  = EWT + (size_t)b * 5 * N_DIM;
    const unsigned int* svw = (const unsigned int*)sv;

    #pragma unroll
    for (int it = 0; it < 4; ++it) {
        const int g  = it * 256 + tid;          // float4 index
        const int m0 = g * 4;
        const float4 x = *(const float4*)(xrow + m0);
        unsigned int u0 = svw[2 * g + 1];
        unsigned int u1 = svw[2 * g + 2];
        unsigned int u2 = svw[2 * g + 3];
        unsigned int u3 = svw[2 * g + 4];
        float w8[8];
        w8[0] = b2f(u0 & 0xffff); w8[1] = b2f(u0 >> 16);
        w8[2] = b2f(u1 & 0xffff); w8[3] = b2f(u1 >> 16);
        w8[4] = b2f(u2 & 0xffff); w8[5] = b2f(u2 >> 16);
        w8[6] = b2f(u3 & 0xffff); w8[7] = b2f(u3 >> 16);
        const float4 t0 = *(const float4*)(ewt + 0 * N_DIM + m0);
        const float4 t1 = *(const float4*)(ewt + 1 * N_DIM + m0);
        const float4 t2 = *(const float4*)(ewt + 2 * N_DIM + m0);
        const float4 t3 = *(const float4*)(ewt + 3 * N_DIM + m0);
        const float4 t4 = *(const float4*)(ewt + 4 * N_DIM + m0);
        float4 r;
        r.x = x.x + S + w8[0]*t0.x + w8[1]*t1.x + w8[2]*t2.x + w8[3]*t3.x + w8[4]*t4.x;
        r.y = x.y + S + w8[1]*t0.y + w8[2]*t1.y + w8[3]*t2.y + w8[4]*t3.y + w8[5]*t4.y;
        r.z = x.z + S + w8[2]*t0.z + w8[3]*t1.z + w8[4]*t2.z + w8[5]*t3.z + w8[6]*t4.z;
        r.w = x.w + S + w8[3]*t0.w + w8[4]*t1.w + w8[5]*t2.w + w8[6]*t3.w + w8[7]*t4.w;
        *(float4*)(orow + m0) = r;
    }
}

// ---------------------------------------------------------------------------
extern "C" void kernel_launch(void* const* d_in, const int* in_sizes, int n_in,
                              void* d_out, int out_size, void* d_ws, size_t ws_size,
                              hipStream_t stream)
{
    const float* X  = (const float*)d_in[0];   // [B,C,N]
    const float* H  = (const float*)d_in[1];   // [B,R,N]
    const float* Wk = (const float*)d_in[2];   // [R,C]
    const float* Wv = (const float*)d_in[3];   // [C,C]
    float* out = (float*)d_out;

    const size_t TENS = (size_t)B_DIM * C_DIM * N_DIM;   // 4194304
    unsigned short* XT  = (unsigned short*)d_ws;         // bf16 [b][n][c]
    unsigned short* Wkb = XT  + TENS;                    // 65536
    unsigned short* Wvb = Wkb + 65536;
    unsigned short* Kb  = Wvb + 65536;                   // bf16 [b][r][n]
    unsigned short* Vb  = Kb  + TENS;
    float* EWT = (float*)(Vb + TENS);                    // [b][5][m]
    float* Wn  = EWT + (size_t)B_DIM * 5 * N_DIM;        // [b][n]

    castW<<<dim3(32, 2),                         256, 0, stream>>>(Wk, Wv, Wkb, Wvb);
    castX<<<dim3(N_DIM / 64, C_DIM / 64, B_DIM), 256, 0, stream>>>(X, XT);
    gemm_kv<<<dim3(N_DIM / 128, C_DIM / 64, B_DIM), 256, 0, stream>>>(
        XT, Wkb, Wvb, Kb, Vb);
    scores<<<dim3(N_DIM / 32, B_DIM),            512, 0, stream>>>(H, Kb, EWT, Wn);
    epi<<<dim3(C_DIM, B_DIM),                    256, 0, stream>>>(X, Vb, EWT, Wn, out);
}